// Round 10
// baseline (366.480 us; speedup 1.0000x reference)
//
#include <hip/hip_runtime.h>

// log2(1e-7): frac < 1e-7  <=>  log2(frac) < this
#define LOG2_EPS_CLAMP -23.2534966f

__device__ __forceinline__ float flog2(float x) { return __builtin_amdgcn_logf(x); }

// 8 waves/block (512 thr); wave s owns i in {2s,2s+1} for the block's 64
// neurons (one per lane). Raw bins stay in REGISTERS between phases:
// phase 2 has zero global-memory traffic. m12 reduced via LDS atomics.
__global__ __launch_bounds__(512) void pid_kernel(const float* __restrict__ p,
                                                  float* __restrict__ out,
                                                  const int N) {
    __shared__ float m12buf[32][64];     // full m12 (8 KB), LDS atomics
    __shared__ float ibuf[3][8][64];     // I1/I2/I4 per-wave partials (6 KB)

    const int tid = threadIdx.x;
    const int g   = tid & 63;            // neuron offset in block
    const int s   = tid >> 6;            // wave id 0..7, owns i = 2s, 2s+1
    const int n   = blockIdx.x * 64 + g;
    const bool active = (n < N);

    // zero atomic target: 2048 floats / 512 threads
    #pragma unroll
    for (int t = 0; t < 4; ++t) ((float*)m12buf)[t * 512 + tid] = 0.f;
    __syncthreads();

    const float* __restrict__ q = p + n;

    // ---- phase 1: load own 64 bins into registers (coalesced 256B segs) ----
    float f0a[2][16], f1a[2][16];
    if (active) {
        #pragma unroll
        for (int ii = 0; ii < 2; ++ii) {
            const float* __restrict__ qi = q + (size_t)((2 * s + ii) * 32) * (size_t)N;
            #pragma unroll
            for (int j = 0; j < 16; ++j) {
                f0a[ii][j] = qi[(size_t)(2 * j) * (size_t)N];
                f1a[ii][j] = qi[(size_t)(2 * j + 1) * (size_t)N];
            }
        }
        #pragma unroll
        for (int j = 0; j < 16; ++j) {
            atomicAdd(&m12buf[2 * j][g],     f0a[0][j] + f0a[1][j]);
            atomicAdd(&m12buf[2 * j + 1][g], f1a[0][j] + f1a[1][j]);
        }
    } else {
        #pragma unroll
        for (int ii = 0; ii < 2; ++ii)
            #pragma unroll
            for (int j = 0; j < 16; ++j) { f0a[ii][j] = 0.f; f1a[ii][j] = 0.f; }
    }
    __syncthreads();

    // P2 marginal (2 values) from LDS
    float P20 = 0.f, P21 = 0.f;
    #pragma unroll
    for (int j = 0; j < 16; ++j) { P20 += m12buf[2 * j][g]; P21 += m12buf[2 * j + 1][g]; }
    const float LP20 = flog2(P20);
    const float LP21 = flog2(P21);

    // own-i m02 slices from registers
    float a0[2], a1[2];
    #pragma unroll
    for (int ii = 0; ii < 2; ++ii) {
        float s0 = 0.f, s1 = 0.f;
        #pragma unroll
        for (int j = 0; j < 16; ++j) { s0 += f0a[ii][j]; s1 += f1a[ii][j]; }
        a0[ii] = s0; a1[ii] = s1;
    }

    // ---- phase 2: I1, I4, I2 — registers + LDS only ----
    float I1 = 0.f, I2 = 0.f, I4 = 0.f;
    #pragma unroll
    for (int ii = 0; ii < 2; ++ii) {
        const float a0i = a0[ii], a1i = a1[ii];
        const float m0i = a0i + a1i;
        #pragma unroll
        for (int j = 0; j < 16; ++j) {
            const float w0 = m12buf[2 * j][g];       // 2-way bank alias: free
            const float w1 = m12buf[2 * j + 1][g];
            const float f0  = f0a[ii][j];
            const float f1  = f1a[ii][j];
            const float p01 = f0 + f1;
            const float u1  = m0i + (w0 + w1) - p01;
            const float Lu1  = flog2(u1);
            const float Lp01 = flog2(p01);
            // k = 0
            {
                const float num = a0i + w0 - f0;
                float l1 = flog2(num) - Lu1 - LP20;
                l1 = (l1 < LOG2_EPS_CLAMP) ? 0.f : l1;
                I1 = fmaf(f0, l1, I1);
                float l4 = flog2(f0) - Lp01 - LP20;
                l4 = (l4 < LOG2_EPS_CLAMP) ? 0.f : l4;
                I4 = fmaf(f0, l4, I4);
            }
            // k = 1
            {
                const float num = a1i + w1 - f1;
                float l1 = flog2(num) - Lu1 - LP21;
                l1 = (l1 < LOG2_EPS_CLAMP) ? 0.f : l1;
                I1 = fmaf(f1, l1, I1);
                float l4 = flog2(f1) - Lp01 - LP21;
                l4 = (l4 < LOG2_EPS_CLAMP) ? 0.f : l4;
                I4 = fmaf(f1, l4, I4);
            }
        }
        // I2 contribution of this i
        const float L0 = flog2(m0i);
        float la = flog2(a0i) - L0 - LP20;
        la = (la < LOG2_EPS_CLAMP) ? 0.f : la;
        I2 = fmaf(a0i, la, I2);
        float lb = flog2(a1i) - L0 - LP21;
        lb = (lb < LOG2_EPS_CLAMP) ? 0.f : lb;
        I2 = fmaf(a1i, lb, I2);
    }
    ibuf[0][s][g] = I1;
    ibuf[1][s][g] = I2;
    ibuf[2][s][g] = I4;
    __syncthreads();

    if (s == 0 && active) {
        float r1 = 0.f, r2 = 0.f, r4 = 0.f;
        #pragma unroll
        for (int w = 0; w < 8; ++w) {
            r1 += ibuf[0][w][g];
            r2 += ibuf[1][w][g];
            r4 += ibuf[2][w][g];
        }

        // I3 = I(X1;Y) from full m12
        float I3 = 0.f;
        #pragma unroll
        for (int j = 0; j < 16; ++j) {
            const float w0 = m12buf[2 * j][g];
            const float w1 = m12buf[2 * j + 1][g];
            const float L1 = flog2(w0 + w1);
            float la = flog2(w0) - L1 - LP20;
            la = (la < LOG2_EPS_CLAMP) ? 0.f : la;
            I3 = fmaf(w0, la, I3);
            float lb = flog2(w1) - L1 - LP21;
            lb = (lb < LOG2_EPS_CLAMP) ? 0.f : lb;
            I3 = fmaf(w1, lb, I3);
        }
        const float H = -(P20 * flog2(P20 + 1e-10f) + P21 * flog2(P21 + 1e-10f));

        out[0 * N + n] = r1;
        out[1 * N + n] = r2 - r1;
        out[2 * N + n] = I3 - r1;
        out[3 * N + n] = r1 - r2 - I3 + r4;
        out[4 * N + n] = H - r4;
    }
}

extern "C" void kernel_launch(void* const* d_in, const int* in_sizes, int n_in,
                              void* d_out, int out_size, void* d_ws, size_t ws_size,
                              hipStream_t stream) {
    const float* p = (const float*)d_in[0];
    float* out = (float*)d_out;
    const int N = in_sizes[0] / 512;          // (16*16*2) bins per neuron
    const int blocks = (N + 63) / 64;         // 64 neurons per 512-thread block
    pid_kernel<<<blocks, 512, 0, stream>>>(p, out, N);
}